// Round 1
// baseline (555.186 us; speedup 1.0000x reference)
//
#include <hip/hip_runtime.h>
#include <hip/hip_bf16.h>

#define SDIM 1024
#define DDIM 768
#define HEADS 12
#define DHD 64
#define MLPD 3072
#define BSZ 8
#define SB (BSZ*SDIM)

typedef unsigned short u16;
typedef unsigned int u32;
typedef __attribute__((ext_vector_type(8))) short short8;
typedef __attribute__((ext_vector_type(4))) float f32x4;
typedef __attribute__((ext_vector_type(4))) u16 u16x4;
typedef __attribute__((ext_vector_type(4))) u32 u32x4;
typedef __attribute__((ext_vector_type(4))) float float4x;

__device__ __forceinline__ u16 f2b(float f) {
  u32 u = __float_as_uint(f);
  u = (u + 0x7fffu + ((u >> 16) & 1u)) >> 16;
  return (u16)u;
}

// ---- weight transpose fp32[K][N] -> bf16[N][K] ----
__global__ __launch_bounds__(256) void transpose_w(const float* __restrict__ src,
                                                   u16* __restrict__ dst,
                                                   int K, int N) {
  __shared__ float tile[32][33];
  const int tx = threadIdx.x & 31, ty = threadIdx.x >> 5;
  const int n0 = blockIdx.x * 32, k0 = blockIdx.y * 32;
#pragma unroll
  for (int i = 0; i < 4; ++i)
    tile[ty + i * 8][tx] = src[(size_t)(k0 + ty + i * 8) * N + n0 + tx];
  __syncthreads();
#pragma unroll
  for (int i = 0; i < 4; ++i)
    dst[(size_t)(n0 + ty + i * 8) * K + k0 + tx] = f2b(tile[tx][ty + i * 8]);
}

__global__ void bias_concat(const float* __restrict__ bq, const float* __restrict__ bk,
                            const float* __restrict__ bv, float* __restrict__ dst) {
  int i = blockIdx.x * 256 + threadIdx.x;
  if (i < 3 * DDIM)
    dst[i] = (i < DDIM) ? bq[i] : (i < 2 * DDIM) ? bk[i - DDIM] : bv[i - 2 * DDIM];
}

// ---- layernorm f32 -> bf16, one wave per row ----
__global__ __launch_bounds__(256) void ln_kernel(const float* __restrict__ x,
                                                 const float* __restrict__ g,
                                                 const float* __restrict__ b,
                                                 u16* __restrict__ y) {
  const int row = blockIdx.x * 4 + (threadIdx.x >> 6);
  const int lane = threadIdx.x & 63;
  const float4x* xp = (const float4x*)(x + (size_t)row * DDIM);
  float4x v[3];
  float sum = 0.f, sq = 0.f;
#pragma unroll
  for (int i = 0; i < 3; ++i) {
    v[i] = xp[lane + i * 64];
#pragma unroll
    for (int j = 0; j < 4; ++j) { sum += v[i][j]; sq += v[i][j] * v[i][j]; }
  }
#pragma unroll
  for (int m = 1; m < 64; m <<= 1) {
    sum += __shfl_xor(sum, m, 64);
    sq  += __shfl_xor(sq, m, 64);
  }
  const float mu = sum * (1.f / DDIM);
  const float var = sq * (1.f / DDIM) - mu * mu;
  const float rstd = rsqrtf(var + 1e-6f);
  const float4x* gp = (const float4x*)g;
  const float4x* bp = (const float4x*)b;
  u16x4* yp = (u16x4*)(y + (size_t)row * DDIM);
#pragma unroll
  for (int i = 0; i < 3; ++i) {
    float4x gg = gp[lane + i * 64], bb = bp[lane + i * 64];
    u16x4 o;
#pragma unroll
    for (int j = 0; j < 4; ++j) o[j] = f2b((v[i][j] - mu) * rstd * gg[j] + bb[j]);
    yp[lane + i * 64] = o;
  }
}

// ---- GEMM: C[M,N] = A[M,K] (bf16) @ Bt[N,K]^T (bf16), fp32 accum ----
// EP 0: QKV scatter (bias, ->q/k/vT bf16)   EP 1: +bias+res -> f32   EP 2: +bias, relu -> bf16
template <int EP>
__global__ __launch_bounds__(256) void gemm_bf16(
    const u16* __restrict__ A, const u16* __restrict__ Bt,
    int M, int N, int K,
    const float* __restrict__ bias, const float* __restrict__ res,
    float* __restrict__ outF, u16* __restrict__ o0, u16* __restrict__ o1,
    u16* __restrict__ o2) {
  __shared__ u16 As[128 * 40];
  __shared__ u16 Bs[128 * 40];
  const int tid = threadIdx.x;
  const int lane = tid & 63, wid = tid >> 6;
  const int l15 = lane & 15, lg = lane >> 4;
  const int wm = wid >> 1, wn = wid & 1;
  const int m0 = blockIdx.x * 128, n0 = blockIdx.y * 128;
  const int lrow = tid >> 2, lcol = (tid & 3) * 8;

  f32x4 acc[4][4] = {};

  for (int k0 = 0; k0 < K; k0 += 32) {
    u32x4 a0 = *(const u32x4*)&A[(size_t)(m0 + lrow) * K + k0 + lcol];
    u32x4 a1 = *(const u32x4*)&A[(size_t)(m0 + 64 + lrow) * K + k0 + lcol];
    u32x4 b0 = *(const u32x4*)&Bt[(size_t)(n0 + lrow) * K + k0 + lcol];
    u32x4 b1 = *(const u32x4*)&Bt[(size_t)(n0 + 64 + lrow) * K + k0 + lcol];
    __syncthreads();
    *(u32x4*)&As[lrow * 40 + lcol] = a0;
    *(u32x4*)&As[(lrow + 64) * 40 + lcol] = a1;
    *(u32x4*)&Bs[lrow * 40 + lcol] = b0;
    *(u32x4*)&Bs[(lrow + 64) * 40 + lcol] = b1;
    __syncthreads();
    short8 af[4], bfr[4];
#pragma unroll
    for (int i = 0; i < 4; ++i)
      af[i] = *(const short8*)&As[(wm * 64 + i * 16 + l15) * 40 + 8 * lg];
#pragma unroll
    for (int i = 0; i < 4; ++i)
      bfr[i] = *(const short8*)&Bs[(wn * 64 + i * 16 + l15) * 40 + 8 * lg];
#pragma unroll
    for (int im = 0; im < 4; ++im)
#pragma unroll
      for (int in = 0; in < 4; ++in)
        acc[im][in] = __builtin_amdgcn_mfma_f32_16x16x32_bf16(af[im], bfr[in], acc[im][in], 0, 0, 0);
  }

#pragma unroll
  for (int im = 0; im < 4; ++im) {
#pragma unroll
    for (int in = 0; in < 4; ++in) {
      const int gn = n0 + wn * 64 + in * 16 + l15;
#pragma unroll
      for (int r = 0; r < 4; ++r) {
        const int gm = m0 + wm * 64 + im * 16 + lg * 4 + r;
        float v = acc[im][in][r];
        if (EP == 0) {
          v += bias[gn];
          const int sel = gn / DDIM;
          const int d = gn - sel * DDIM;
          const int h = d >> 6, dh = d & 63;
          const int bb = gm >> 10, ss = gm & 1023;
          const u16 bv = f2b(v);
          const int bhid = bb * HEADS + h;
          if (sel == 0)      o0[((size_t)bhid * SDIM + ss) * DHD + dh] = bv;
          else if (sel == 1) o1[((size_t)bhid * SDIM + ss) * DHD + dh] = bv;
          else               o2[((size_t)bhid * DHD + dh) * SDIM + ss] = bv;
        } else if (EP == 1) {
          const size_t idx = (size_t)gm * N + gn;
          outF[idx] = v + bias[gn] + res[idx];
        } else {
          const size_t idx = (size_t)gm * N + gn;
          o0[idx] = f2b(fmaxf(v + bias[gn], 0.f));
        }
      }
    }
  }
}

// ---- flash attention: grid (S/64, B*H), 4 waves x 16 q-rows ----
__global__ __launch_bounds__(256) void attn_kernel(const u16* __restrict__ Q,
                                                   const u16* __restrict__ Km,
                                                   const u16* __restrict__ Vt,
                                                   u16* __restrict__ ctx) {
  __shared__ u16 P_lds[4][16][72];
  const int bh = blockIdx.y;
  const int qblk = blockIdx.x;
  const int wid = threadIdx.x >> 6, lane = threadIdx.x & 63;
  const int l15 = lane & 15, lg = lane >> 4;
  const int q0 = qblk * 64 + wid * 16;
  const float sc = (q0 >= 512) ? 0.f : 0.125f;

  const u16* Qp = Q + (size_t)bh * SDIM * DHD;
  const u16* Kp = Km + (size_t)bh * SDIM * DHD;
  const u16* Vp = Vt + (size_t)bh * DHD * SDIM;

  short8 aq[2];
  aq[0] = *(const short8*)&Qp[(q0 + l15) * DHD + 8 * lg];
  aq[1] = *(const short8*)&Qp[(q0 + l15) * DHD + 32 + 8 * lg];

  float mrow[4], lrow[4];
  f32x4 o_acc[4] = {};
#pragma unroll
  for (int r = 0; r < 4; ++r) { mrow[r] = -1e30f; lrow[r] = 0.f; }

  for (int kb = 0; kb < SDIM / 64; ++kb) {
    f32x4 s_acc[4] = {};
    const u16* kbase = Kp + (size_t)kb * 64 * DHD;
#pragma unroll
    for (int in = 0; in < 4; ++in) {
      short8 b0 = *(const short8*)&kbase[(in * 16 + l15) * DHD + 8 * lg];
      short8 b1 = *(const short8*)&kbase[(in * 16 + l15) * DHD + 32 + 8 * lg];
      s_acc[in] = __builtin_amdgcn_mfma_f32_16x16x32_bf16(aq[0], b0, s_acc[in], 0, 0, 0);
      s_acc[in] = __builtin_amdgcn_mfma_f32_16x16x32_bf16(aq[1], b1, s_acc[in], 0, 0, 0);
    }
#pragma unroll
    for (int in = 0; in < 4; ++in)
#pragma unroll
      for (int r = 0; r < 4; ++r) s_acc[in][r] *= sc;

    float alpha[4], rsum[4];
#pragma unroll
    for (int r = 0; r < 4; ++r) {
      float v = -1e30f;
#pragma unroll
      for (int in = 0; in < 4; ++in) v = fmaxf(v, s_acc[in][r]);
#pragma unroll
      for (int m = 1; m < 16; m <<= 1) v = fmaxf(v, __shfl_xor(v, m, 64));
      const float mn = fmaxf(mrow[r], v);
      alpha[r] = __expf(mrow[r] - mn);
      mrow[r] = mn;
      rsum[r] = 0.f;
    }
#pragma unroll
    for (int in = 0; in < 4; ++in)
#pragma unroll
      for (int r = 0; r < 4; ++r) {
        const float p = __expf(s_acc[in][r] - mrow[r]);
        rsum[r] += p;
        P_lds[wid][lg * 4 + r][in * 16 + l15] = f2b(p);
      }
#pragma unroll
    for (int r = 0; r < 4; ++r) {
      float v = rsum[r];
#pragma unroll
      for (int m = 1; m < 16; m <<= 1) v += __shfl_xor(v, m, 64);
      lrow[r] = lrow[r] * alpha[r] + v;
    }
#pragma unroll
    for (int in = 0; in < 4; ++in)
#pragma unroll
      for (int r = 0; r < 4; ++r) o_acc[in][r] *= alpha[r];

    short8 ap0 = *(const short8*)&P_lds[wid][l15][8 * lg];
    short8 ap1 = *(const short8*)&P_lds[wid][l15][32 + 8 * lg];
    const u16* vbase = Vp + kb * 64;
#pragma unroll
    for (int in = 0; in < 4; ++in) {
      short8 b0 = *(const short8*)&vbase[(size_t)(in * 16 + l15) * SDIM + 8 * lg];
      short8 b1 = *(const short8*)&vbase[(size_t)(in * 16 + l15) * SDIM + 32 + 8 * lg];
      o_acc[in] = __builtin_amdgcn_mfma_f32_16x16x32_bf16(ap0, b0, o_acc[in], 0, 0, 0);
      o_acc[in] = __builtin_amdgcn_mfma_f32_16x16x32_bf16(ap1, b1, o_acc[in], 0, 0, 0);
    }
  }
  const int bb = bh / HEADS, h = bh - bb * HEADS;
#pragma unroll
  for (int in = 0; in < 4; ++in)
#pragma unroll
    for (int r = 0; r < 4; ++r) {
      const int s = q0 + lg * 4 + r;
      const float v = o_acc[in][r] / lrow[r];
      ctx[((size_t)(bb * SDIM + s)) * DDIM + h * 64 + in * 16 + l15] = f2b(v);
    }
}

extern "C" void kernel_launch(void* const* d_in, const int* in_sizes, int n_in,
                              void* d_out, int out_size, void* d_ws, size_t ws_size,
                              hipStream_t stream) {
  const float* x    = (const float*)d_in[0];
  const float* Wq   = (const float*)d_in[1];
  const float* bq   = (const float*)d_in[2];
  const float* Wk   = (const float*)d_in[3];
  const float* bk   = (const float*)d_in[4];
  const float* Wv   = (const float*)d_in[5];
  const float* bv   = (const float*)d_in[6];
  const float* Wo   = (const float*)d_in[7];
  const float* bo   = (const float*)d_in[8];
  const float* ln1g = (const float*)d_in[9];
  const float* ln1b = (const float*)d_in[10];
  const float* ln2g = (const float*)d_in[11];
  const float* ln2b = (const float*)d_in[12];
  const float* W1   = (const float*)d_in[13];
  const float* b1   = (const float*)d_in[14];
  const float* W2   = (const float*)d_in[15];
  const float* b2   = (const float*)d_in[16];

  char* ws = (char*)d_ws;
  u16* xn1   = (u16*)(ws + 0);
  u16* qb    = (u16*)(ws + 12582912);
  u16* kbuf  = (u16*)(ws + 25165824);
  u16* vtb   = (u16*)(ws + 37748736);
  u16* h1    = (u16*)(ws + 0);  // overlays xn1/q/k/vT (all dead by MLP1)
  u16* ctx   = (u16*)(ws + 50331648);
  float* x2  = (float*)(ws + 62914560);
  u16* xn2   = (u16*)(ws + 88080384);
  u16* wqkvT = (u16*)(ws + 100663296);
  u16* woT   = (u16*)(ws + 104202240);
  u16* w1T   = (u16*)(ws + 105381888);
  u16* w2T   = (u16*)(ws + 110100480);
  float* bqkv = (float*)(ws + 114819072);

  transpose_w<<<dim3(24, 24), 256, 0, stream>>>(Wq, wqkvT, 768, 768);
  transpose_w<<<dim3(24, 24), 256, 0, stream>>>(Wk, wqkvT + 768 * 768, 768, 768);
  transpose_w<<<dim3(24, 24), 256, 0, stream>>>(Wv, wqkvT + 2 * 768 * 768, 768, 768);
  transpose_w<<<dim3(24, 24), 256, 0, stream>>>(Wo, woT, 768, 768);
  transpose_w<<<dim3(96, 24), 256, 0, stream>>>(W1, w1T, 768, 3072);
  transpose_w<<<dim3(24, 96), 256, 0, stream>>>(W2, w2T, 3072, 768);
  bias_concat<<<9, 256, 0, stream>>>(bq, bk, bv, bqkv);

  ln_kernel<<<2048, 256, 0, stream>>>(x, ln1g, ln1b, xn1);
  gemm_bf16<0><<<dim3(64, 18), 256, 0, stream>>>(xn1, wqkvT, 8192, 2304, 768,
                                                 bqkv, nullptr, nullptr, qb, kbuf, vtb);
  attn_kernel<<<dim3(16, 96), 256, 0, stream>>>(qb, kbuf, vtb, ctx);
  gemm_bf16<1><<<dim3(64, 6), 256, 0, stream>>>(ctx, woT, 8192, 768, 768,
                                                bo, x, x2, nullptr, nullptr, nullptr);
  ln_kernel<<<2048, 256, 0, stream>>>(x2, ln2g, ln2b, xn2);
  gemm_bf16<2><<<dim3(64, 24), 256, 0, stream>>>(xn2, w1T, 8192, 3072, 768,
                                                 b1, nullptr, nullptr, h1, nullptr, nullptr);
  gemm_bf16<1><<<dim3(64, 6), 256, 0, stream>>>(h1, w2T, 8192, 768, 3072,
                                                b2, x2, (float*)d_out, nullptr, nullptr, nullptr);
}

// Round 2
// 411.601 us; speedup vs baseline: 1.3488x; 1.3488x over previous
//
#include <hip/hip_runtime.h>
#include <hip/hip_bf16.h>

#define SDIM 1024
#define DDIM 768
#define HEADS 12
#define DHD 64
#define MLPD 3072
#define BSZ 8

typedef unsigned short u16;
typedef unsigned int u32;
typedef __attribute__((ext_vector_type(8))) short short8;
typedef __attribute__((ext_vector_type(4))) float f32x4;
typedef __attribute__((ext_vector_type(4))) u16 u16x4;
typedef __attribute__((ext_vector_type(4))) float float4x;

__device__ __forceinline__ u16 f2b(float f) {
  u32 u = __float_as_uint(f);
  u = (u + 0x7fffu + ((u >> 16) & 1u)) >> 16;
  return (u16)u;
}
__device__ __forceinline__ float b2f(u16 u) {
  return __uint_as_float(((u32)u) << 16);
}

#define GLDS16(g, l)                                                        \
  __builtin_amdgcn_global_load_lds(                                         \
      (const __attribute__((address_space(1))) unsigned int*)(g),           \
      (__attribute__((address_space(3))) unsigned int*)(l), 16, 0, 0)

// ---- weight transpose fp32[K][N] -> bf16[N][K] ----
__global__ __launch_bounds__(256) void transpose_w(const float* __restrict__ src,
                                                   u16* __restrict__ dst,
                                                   int K, int N) {
  __shared__ float tile[32][33];
  const int tx = threadIdx.x & 31, ty = threadIdx.x >> 5;
  const int n0 = blockIdx.x * 32, k0 = blockIdx.y * 32;
#pragma unroll
  for (int i = 0; i < 4; ++i)
    tile[ty + i * 8][tx] = src[(size_t)(k0 + ty + i * 8) * N + n0 + tx];
  __syncthreads();
#pragma unroll
  for (int i = 0; i < 4; ++i)
    dst[(size_t)(n0 + ty + i * 8) * K + k0 + tx] = f2b(tile[tx][ty + i * 8]);
}

__global__ void bias_concat(const float* __restrict__ bq, const float* __restrict__ bk,
                            const float* __restrict__ bv, float* __restrict__ dst) {
  int i = blockIdx.x * 256 + threadIdx.x;
  if (i < 3 * DDIM)
    dst[i] = (i < DDIM) ? bq[i] : (i < 2 * DDIM) ? bk[i - DDIM] : bv[i - 2 * DDIM];
}

// ---- layernorm f32 -> bf16, one wave per row ----
__global__ __launch_bounds__(256) void ln_kernel(const float* __restrict__ x,
                                                 const float* __restrict__ g,
                                                 const float* __restrict__ b,
                                                 u16* __restrict__ y) {
  const int row = blockIdx.x * 4 + (threadIdx.x >> 6);
  const int lane = threadIdx.x & 63;
  const float4x* xp = (const float4x*)(x + (size_t)row * DDIM);
  float4x v[3];
  float sum = 0.f, sq = 0.f;
#pragma unroll
  for (int i = 0; i < 3; ++i) {
    v[i] = xp[lane + i * 64];
#pragma unroll
    for (int j = 0; j < 4; ++j) { sum += v[i][j]; sq += v[i][j] * v[i][j]; }
  }
#pragma unroll
  for (int m = 1; m < 64; m <<= 1) {
    sum += __shfl_xor(sum, m, 64);
    sq  += __shfl_xor(sq, m, 64);
  }
  const float mu = sum * (1.f / DDIM);
  const float var = sq * (1.f / DDIM) - mu * mu;
  const float rstd = rsqrtf(var + 1e-6f);
  const float4x* gp = (const float4x*)g;
  const float4x* bp = (const float4x*)b;
  u16x4* yp = (u16x4*)(y + (size_t)row * DDIM);
#pragma unroll
  for (int i = 0; i < 3; ++i) {
    float4x gg = gp[lane + i * 64], bb = bp[lane + i * 64];
    u16x4 o;
#pragma unroll
    for (int j = 0; j < 4; ++j) o[j] = f2b((v[i][j] - mu) * rstd * gg[j] + bb[j]);
    yp[lane + i * 64] = o;
  }
}

// ---- GEMM (m97 structure): C[M,N] = A[M,K] bf16 @ Bt[N,K]^T, global_load_lds staging ----
// EP 0: QKV scatter   EP 1: +bias+res -> f32   EP 2: +bias, relu -> bf16
template <int EP>
__global__ __launch_bounds__(256) void gemm_bf16(
    const u16* __restrict__ A, const u16* __restrict__ Bt,
    int M, int N, int K,
    const float* __restrict__ bias, const float* __restrict__ res,
    float* __restrict__ outF, u16* __restrict__ o0, u16* __restrict__ o1,
    u16* __restrict__ o2) {
  __shared__ u16 As[128 * 32];
  __shared__ u16 Bs[128 * 32];
  const int tid = threadIdx.x;
  const int lane = tid & 63, wid = tid >> 6;
  const int l15 = lane & 15, lg = lane >> 4;
  const int wm = wid >> 1, wn = wid & 1;
  const int m0 = blockIdx.x * 128, n0 = blockIdx.y * 128;

  const u16* ag = A + (size_t)(m0 + (tid >> 2)) * K + (tid & 3) * 8;
  const u16* bg = Bt + (size_t)(n0 + (tid >> 2)) * K + (tid & 3) * 8;
  u16* lA = As + tid * 8;
  u16* lB = Bs + tid * 8;
  const size_t half = (size_t)64 * K;

  f32x4 acc[4][4] = {};

  for (int k0 = 0; k0 < K; k0 += 32) {
    __syncthreads();  // previous iter's LDS reads complete
    GLDS16(ag + k0, lA);
    GLDS16(ag + half + k0, lA + 2048);
    GLDS16(bg + k0, lB);
    GLDS16(bg + half + k0, lB + 2048);
    __syncthreads();  // drains vmcnt(0): tiles staged
    short8 af[4], bfr[4];
#pragma unroll
    for (int i = 0; i < 4; ++i)
      af[i] = *(const short8*)&As[(wm * 64 + i * 16 + l15) * 32 + 8 * lg];
#pragma unroll
    for (int i = 0; i < 4; ++i)
      bfr[i] = *(const short8*)&Bs[(wn * 64 + i * 16 + l15) * 32 + 8 * lg];
#pragma unroll
    for (int im = 0; im < 4; ++im)
#pragma unroll
      for (int in = 0; in < 4; ++in)
        acc[im][in] = __builtin_amdgcn_mfma_f32_16x16x32_bf16(af[im], bfr[in], acc[im][in], 0, 0, 0);
  }

#pragma unroll
  for (int im = 0; im < 4; ++im) {
#pragma unroll
    for (int in = 0; in < 4; ++in) {
      const int gn = n0 + wn * 64 + in * 16 + l15;
#pragma unroll
      for (int r = 0; r < 4; ++r) {
        const int gm = m0 + wm * 64 + im * 16 + lg * 4 + r;
        float v = acc[im][in][r];
        if (EP == 0) {
          v += bias[gn];
          const int sel = gn / DDIM;
          const int d = gn - sel * DDIM;
          const int h = d >> 6, dh = d & 63;
          const int bb = gm >> 10, ss = gm & 1023;
          const u16 bv = f2b(v);
          const int bhid = bb * HEADS + h;
          if (sel == 0)      o0[((size_t)bhid * SDIM + ss) * DHD + dh] = bv;
          else if (sel == 1) o1[((size_t)bhid * SDIM + ss) * DHD + dh] = bv;
          else               o2[((size_t)bhid * DHD + dh) * SDIM + ss] = bv;
        } else if (EP == 1) {
          const size_t idx = (size_t)gm * N + gn;
          outF[idx] = v + bias[gn] + res[idx];
        } else {
          const size_t idx = (size_t)gm * N + gn;
          o0[idx] = f2b(fmaxf(v + bias[gn], 0.f));
        }
      }
    }
  }
}

// ---- flash attention for q rows < 512: grid (8, B*H), 4 waves x 16 q-rows ----
// K/V tiles LDS-staged (XOR-swizzled via pre-swizzled global src), double-buffered.
__global__ __launch_bounds__(256) void attn_kernel(const u16* __restrict__ Q,
                                                   const u16* __restrict__ Km,
                                                   const u16* __restrict__ Vt,
                                                   u16* __restrict__ ctx) {
  __shared__ u16 Ks[2][4096];
  __shared__ u16 Vs[2][4096];
  __shared__ u16 P_lds[4][16][72];
  const int bh = blockIdx.y;
  const int tid = threadIdx.x;
  const int wid = tid >> 6, lane = tid & 63;
  const int l15 = lane & 15, lg = lane >> 4;
  const int q0 = blockIdx.x * 64 + wid * 16;

  const u16* Qp = Q + (size_t)bh * SDIM * DHD;
  const char* Kp = (const char*)(Km + (size_t)bh * SDIM * DHD);
  const char* Vp = (const char*)(Vt + (size_t)bh * DHD * SDIM);

  // per-lane staging geometry (2 issues of 16B per tile per matrix)
  int so[2], vo_base[2], ldso[2];
#pragma unroll
  for (int j = 0; j < 2; ++j) {
    const int o = j * 4096 + tid * 16;   // linear LDS byte offset
    const int row = o >> 7;              // logical row (128B rows)
    ldso[j] = o;
    so[j] = o ^ ((row & 7) << 4);                          // K: global byte within tile
    vo_base[j] = row * 2048 + ((o & 127) ^ ((row & 7) << 4));  // V: + kb*128
  }

  short8 aq0 = *(const short8*)&Qp[(q0 + l15) * DHD + 8 * lg];
  short8 aq1 = *(const short8*)&Qp[(q0 + l15) * DHD + 32 + 8 * lg];

  float mrow[4], lrow[4];
  f32x4 o_acc[4] = {};
#pragma unroll
  for (int r = 0; r < 4; ++r) { mrow[r] = -1e30f; lrow[r] = 0.f; }

  // prologue: stage tile 0 into buf 0
#pragma unroll
  for (int j = 0; j < 2; ++j) {
    GLDS16(Kp + so[j], (char*)&Ks[0][0] + ldso[j]);
    GLDS16(Vp + vo_base[j], (char*)&Vs[0][0] + ldso[j]);
  }

  for (int kb = 0; kb < 16; ++kb) {
    const int cur = kb & 1;
    if (kb < 15) {
#pragma unroll
      for (int j = 0; j < 2; ++j) {
        GLDS16(Kp + (size_t)(kb + 1) * 8192 + so[j], (char*)&Ks[cur ^ 1][0] + ldso[j]);
        GLDS16(Vp + (size_t)(kb + 1) * 128 + vo_base[j], (char*)&Vs[cur ^ 1][0] + ldso[j]);
      }
      asm volatile("s_waitcnt vmcnt(4)" ::: "memory");
    } else {
      asm volatile("s_waitcnt vmcnt(0)" ::: "memory");
    }
    __builtin_amdgcn_s_barrier();
    __builtin_amdgcn_sched_barrier(0);

    // ---- QK^T ----
    f32x4 s_acc[4] = {};
#pragma unroll
    for (int in = 0; in < 4; ++in) {
      const int row = in * 16 + l15;
      const int a0 = (row * 128 + lg * 16) ^ ((row & 7) << 4);
      const int a1 = (row * 128 + 64 + lg * 16) ^ ((row & 7) << 4);
      short8 b0 = *(const short8*)((const char*)&Ks[cur][0] + a0);
      short8 b1 = *(const short8*)((const char*)&Ks[cur][0] + a1);
      s_acc[in] = __builtin_amdgcn_mfma_f32_16x16x32_bf16(aq0, b0, s_acc[in], 0, 0, 0);
      s_acc[in] = __builtin_amdgcn_mfma_f32_16x16x32_bf16(aq1, b1, s_acc[in], 0, 0, 0);
    }
#pragma unroll
    for (int in = 0; in < 4; ++in)
#pragma unroll
      for (int r = 0; r < 4; ++r) s_acc[in][r] *= 0.125f;

    // ---- online softmax ----
    float alpha[4], rsum[4];
#pragma unroll
    for (int r = 0; r < 4; ++r) {
      float v = -1e30f;
#pragma unroll
      for (int in = 0; in < 4; ++in) v = fmaxf(v, s_acc[in][r]);
#pragma unroll
      for (int m = 1; m < 16; m <<= 1) v = fmaxf(v, __shfl_xor(v, m, 64));
      const float mn = fmaxf(mrow[r], v);
      alpha[r] = __expf(mrow[r] - mn);
      mrow[r] = mn;
      rsum[r] = 0.f;
    }
#pragma unroll
    for (int in = 0; in < 4; ++in)
#pragma unroll
      for (int r = 0; r < 4; ++r) {
        const float p = __expf(s_acc[in][r] - mrow[r]);
        rsum[r] += p;
        P_lds[wid][lg * 4 + r][in * 16 + l15] = f2b(p);
      }
#pragma unroll
    for (int r = 0; r < 4; ++r) {
      float v = rsum[r];
#pragma unroll
      for (int m = 1; m < 16; m <<= 1) v += __shfl_xor(v, m, 64);
      lrow[r] = lrow[r] * alpha[r] + v;
    }
#pragma unroll
    for (int in = 0; in < 4; ++in)
#pragma unroll
      for (int r = 0; r < 4; ++r) o_acc[in][r] *= alpha[r];

    short8 ap0 = *(const short8*)&P_lds[wid][l15][8 * lg];
    short8 ap1 = *(const short8*)&P_lds[wid][l15][32 + 8 * lg];

    // ---- PV ----
#pragma unroll
    for (int in = 0; in < 4; ++in) {
      const int row = in * 16 + l15;
      const int a0 = (row * 128 + lg * 16) ^ ((row & 7) << 4);
      const int a1 = (row * 128 + 64 + lg * 16) ^ ((row & 7) << 4);
      short8 b0 = *(const short8*)((const char*)&Vs[cur][0] + a0);
      short8 b1 = *(const short8*)((const char*)&Vs[cur][0] + a1);
      o_acc[in] = __builtin_amdgcn_mfma_f32_16x16x32_bf16(ap0, b0, o_acc[in], 0, 0, 0);
      o_acc[in] = __builtin_amdgcn_mfma_f32_16x16x32_bf16(ap1, b1, o_acc[in], 0, 0, 0);
    }
    __builtin_amdgcn_sched_barrier(0);
    __builtin_amdgcn_s_barrier();   // buf[cur] reads done before it is restaged
    __builtin_amdgcn_sched_barrier(0);
  }

  const int bb = bh / HEADS, h = bh - bb * HEADS;
#pragma unroll
  for (int in = 0; in < 4; ++in)
#pragma unroll
    for (int r = 0; r < 4; ++r) {
      const int s = q0 + lg * 4 + r;
      const float v = o_acc[in][r] / lrow[r];
      ctx[((size_t)(bb * SDIM + s)) * DDIM + h * 64 + in * 16 + l15] = f2b(v);
    }
}

// ---- rows >= 512: uniform attention = column-mean of V. grid (B*H), 256 thr ----
__global__ __launch_bounds__(256) void meanv_kernel(const u16* __restrict__ Vt,
                                                    u16* __restrict__ ctx) {
  __shared__ float mean_s[64];
  const int bh = blockIdx.x;
  const int t = threadIdx.x;
  const int dh = t >> 2, part = t & 3;
  const u16* vp = Vt + (size_t)bh * DHD * SDIM + (size_t)dh * SDIM + part * 256;
  float s = 0.f;
#pragma unroll
  for (int i = 0; i < 32; ++i) {
    short8 v = *(const short8*)&vp[i * 8];
#pragma unroll
    for (int j = 0; j < 8; ++j) s += b2f((u16)v[j]);
  }
  s += __shfl_xor(s, 1, 64);
  s += __shfl_xor(s, 2, 64);
  if (part == 0) mean_s[dh] = s * (1.f / 1024.f);
  __syncthreads();
  const int b = bh / HEADS, h = bh - b * HEADS;
  u16x4 val;
#pragma unroll
  for (int j = 0; j < 4; ++j) val[j] = f2b(mean_s[(t & 15) * 4 + j]);
#pragma unroll
  for (int i = 0; i < 32; ++i) {
    const int row = 512 + i * 16 + (t >> 4);
    *(u16x4*)&ctx[((size_t)(b * SDIM + row)) * DDIM + h * 64 + (t & 15) * 4] = val;
  }
}

extern "C" void kernel_launch(void* const* d_in, const int* in_sizes, int n_in,
                              void* d_out, int out_size, void* d_ws, size_t ws_size,
                              hipStream_t stream) {
  const float* x    = (const float*)d_in[0];
  const float* Wq   = (const float*)d_in[1];
  const float* bq   = (const float*)d_in[2];
  const float* Wk   = (const float*)d_in[3];
  const float* bk   = (const float*)d_in[4];
  const float* Wv   = (const float*)d_in[5];
  const float* bv   = (const float*)d_in[6];
  const float* Wo   = (const float*)d_in[7];
  const float* bo   = (const float*)d_in[8];
  const float* ln1g = (const float*)d_in[9];
  const float* ln1b = (const float*)d_in[10];
  const float* ln2g = (const float*)d_in[11];
  const float* ln2b = (const float*)d_in[12];
  const float* W1   = (const float*)d_in[13];
  const float* b1   = (const float*)d_in[14];
  const float* W2   = (const float*)d_in[15];
  const float* b2   = (const float*)d_in[16];

  char* ws = (char*)d_ws;
  u16* xn1   = (u16*)(ws + 0);
  u16* qb    = (u16*)(ws + 12582912);
  u16* kbuf  = (u16*)(ws + 25165824);
  u16* vtb   = (u16*)(ws + 37748736);
  u16* h1    = (u16*)(ws + 0);  // overlays xn1/q/k/vT (all dead by MLP1)
  u16* ctx   = (u16*)(ws + 50331648);
  float* x2  = (float*)(ws + 62914560);
  u16* xn2   = (u16*)(ws + 88080384);
  u16* wqkvT = (u16*)(ws + 100663296);
  u16* woT   = (u16*)(ws + 104202240);
  u16* w1T   = (u16*)(ws + 105381888);
  u16* w2T   = (u16*)(ws + 110100480);
  float* bqkv = (float*)(ws + 114819072);

  transpose_w<<<dim3(24, 24), 256, 0, stream>>>(Wq, wqkvT, 768, 768);
  transpose_w<<<dim3(24, 24), 256, 0, stream>>>(Wk, wqkvT + 768 * 768, 768, 768);
  transpose_w<<<dim3(24, 24), 256, 0, stream>>>(Wv, wqkvT + 2 * 768 * 768, 768, 768);
  transpose_w<<<dim3(24, 24), 256, 0, stream>>>(Wo, woT, 768, 768);
  transpose_w<<<dim3(96, 24), 256, 0, stream>>>(W1, w1T, 768, 3072);
  transpose_w<<<dim3(24, 96), 256, 0, stream>>>(W2, w2T, 3072, 768);
  bias_concat<<<9, 256, 0, stream>>>(bq, bk, bv, bqkv);

  ln_kernel<<<2048, 256, 0, stream>>>(x, ln1g, ln1b, xn1);
  gemm_bf16<0><<<dim3(64, 18), 256, 0, stream>>>(xn1, wqkvT, 8192, 2304, 768,
                                                 bqkv, nullptr, nullptr, qb, kbuf, vtb);
  attn_kernel<<<dim3(8, 96), 256, 0, stream>>>(qb, kbuf, vtb, ctx);
  meanv_kernel<<<96, 256, 0, stream>>>(vtb, ctx);
  gemm_bf16<1><<<dim3(64, 6), 256, 0, stream>>>(ctx, woT, 8192, 768, 768,
                                                bo, x, x2, nullptr, nullptr, nullptr);
  ln_kernel<<<2048, 256, 0, stream>>>(x2, ln2g, ln2b, xn2);
  gemm_bf16<2><<<dim3(64, 24), 256, 0, stream>>>(xn2, w1T, 8192, 3072, 768,
                                                 b1, nullptr, nullptr, h1, nullptr, nullptr);
  gemm_bf16<1><<<dim3(64, 6), 256, 0, stream>>>(h1, w2T, 8192, 768, 3072,
                                                b2, x2, (float*)d_out, nullptr, nullptr, nullptr);
}

// Round 3
// 385.450 us; speedup vs baseline: 1.4404x; 1.0678x over previous
//
#include <hip/hip_runtime.h>
#include <hip/hip_bf16.h>

#define SDIM 1024
#define DDIM 768
#define HEADS 12
#define DHD 64
#define MLPD 3072
#define BSZ 8

typedef unsigned short u16;
typedef unsigned int u32;
typedef __attribute__((ext_vector_type(8))) short short8;
typedef __attribute__((ext_vector_type(4))) float f32x4;
typedef __attribute__((ext_vector_type(4))) u16 u16x4;
typedef __attribute__((ext_vector_type(4))) float float4x;

__device__ __forceinline__ u16 f2b(float f) {
  u32 u = __float_as_uint(f);
  u = (u + 0x7fffu + ((u >> 16) & 1u)) >> 16;
  return (u16)u;
}
__device__ __forceinline__ float b2f(u16 u) {
  return __uint_as_float(((u32)u) << 16);
}

#define GLDS16(g, l)                                                        \
  __builtin_amdgcn_global_load_lds(                                         \
      (const __attribute__((address_space(1))) unsigned int*)(g),           \
      (__attribute__((address_space(3))) unsigned int*)(l), 16, 0, 0)

// ---- weight transpose fp32[K][N] -> bf16[N][K] ----
__global__ __launch_bounds__(256) void transpose_w(const float* __restrict__ src,
                                                   u16* __restrict__ dst,
                                                   int K, int N) {
  __shared__ float tile[32][33];
  const int tx = threadIdx.x & 31, ty = threadIdx.x >> 5;
  const int n0 = blockIdx.x * 32, k0 = blockIdx.y * 32;
#pragma unroll
  for (int i = 0; i < 4; ++i)
    tile[ty + i * 8][tx] = src[(size_t)(k0 + ty + i * 8) * N + n0 + tx];
  __syncthreads();
#pragma unroll
  for (int i = 0; i < 4; ++i)
    dst[(size_t)(n0 + ty + i * 8) * K + k0 + tx] = f2b(tile[tx][ty + i * 8]);
}

__global__ void bias_concat(const float* __restrict__ bq, const float* __restrict__ bk,
                            const float* __restrict__ bv, float* __restrict__ dst) {
  int i = blockIdx.x * 256 + threadIdx.x;
  if (i < 3 * DDIM)
    dst[i] = (i < DDIM) ? bq[i] : (i < 2 * DDIM) ? bk[i - DDIM] : bv[i - 2 * DDIM];
}

// ---- layernorm f32 -> bf16, one wave per row ----
__global__ __launch_bounds__(256) void ln_kernel(const float* __restrict__ x,
                                                 const float* __restrict__ g,
                                                 const float* __restrict__ b,
                                                 u16* __restrict__ y) {
  const int row = blockIdx.x * 4 + (threadIdx.x >> 6);
  const int lane = threadIdx.x & 63;
  const float4x* xp = (const float4x*)(x + (size_t)row * DDIM);
  float4x v[3];
  float sum = 0.f, sq = 0.f;
#pragma unroll
  for (int i = 0; i < 3; ++i) {
    v[i] = xp[lane + i * 64];
#pragma unroll
    for (int j = 0; j < 4; ++j) { sum += v[i][j]; sq += v[i][j] * v[i][j]; }
  }
#pragma unroll
  for (int m = 1; m < 64; m <<= 1) {
    sum += __shfl_xor(sum, m, 64);
    sq  += __shfl_xor(sq, m, 64);
  }
  const float mu = sum * (1.f / DDIM);
  const float var = sq * (1.f / DDIM) - mu * mu;
  const float rstd = rsqrtf(var + 1e-6f);
  const float4x* gp = (const float4x*)g;
  const float4x* bp = (const float4x*)b;
  u16x4* yp = (u16x4*)(y + (size_t)row * DDIM);
#pragma unroll
  for (int i = 0; i < 3; ++i) {
    float4x gg = gp[lane + i * 64], bb = bp[lane + i * 64];
    u16x4 o;
#pragma unroll
    for (int j = 0; j < 4; ++j) o[j] = f2b((v[i][j] - mu) * rstd * gg[j] + bb[j]);
    yp[lane + i * 64] = o;
  }
}

// ---- GEMM: BK=64, XOR-swizzled LDS (pre-swizzled global src), dbuf + counted vmcnt ----
// EP 0: QKV scatter   EP 1: +bias+res -> f32   EP 2: +bias, relu -> bf16
template <int EP>
__global__ __launch_bounds__(256) void gemm_bf16(
    const u16* __restrict__ A, const u16* __restrict__ Bt,
    int M, int N, int K,
    const float* __restrict__ bias, const float* __restrict__ res,
    float* __restrict__ outF, u16* __restrict__ o0, u16* __restrict__ o1,
    u16* __restrict__ o2) {
  __shared__ u16 As[2][128 * 64];
  __shared__ u16 Bs[2][128 * 64];
  const int tid = threadIdx.x;
  const int lane = tid & 63, wid = tid >> 6;
  const int l15 = lane & 15, lg = lane >> 4;
  const int wm = wid >> 1, wn = wid & 1;
  const int m0 = blockIdx.x * 128, n0 = blockIdx.y * 128;

  // staging: linear LDS dest (row = tid>>3 (+32j), 16B slot = tid&7),
  // global source pre-swizzled by the same XOR the reads use.
  const int srow = tid >> 3;
  const int scb = ((tid & 7) << 4) ^ ((srow & 7) << 4);
  const u16* ag = A + (size_t)(m0 + srow) * K + (scb >> 1);
  const u16* bg = Bt + (size_t)(n0 + srow) * K + (scb >> 1);

  f32x4 acc[4][4] = {};
  const int NT = K >> 6;

#define STAGE_G(buf, koff)                                                    \
  {                                                                           \
    _Pragma("unroll") for (int j = 0; j < 4; ++j)                             \
        GLDS16(ag + (koff) + (size_t)j * 32 * K, &As[buf][tid * 8 + j * 2048]); \
    _Pragma("unroll") for (int j = 0; j < 4; ++j)                             \
        GLDS16(bg + (koff) + (size_t)j * 32 * K, &Bs[buf][tid * 8 + j * 2048]); \
  }

  STAGE_G(0, 0);
  int cur = 0;
  for (int t = 0; t < NT; ++t) {
    if (t + 1 < NT) {
      STAGE_G(cur ^ 1, (t + 1) * 64);
      asm volatile("s_waitcnt vmcnt(8)" ::: "memory");  // tile t done; t+1 in flight
    } else {
      asm volatile("s_waitcnt vmcnt(0)" ::: "memory");
    }
    __builtin_amdgcn_s_barrier();
    __builtin_amdgcn_sched_barrier(0);
    const char* ab = (const char*)As[cur];
    const char* bb = (const char*)Bs[cur];
    short8 af[4][2], bf[4][2];
#pragma unroll
    for (int i = 0; i < 4; ++i) {
      const int row = wm * 64 + i * 16 + l15;
      const int rx = (l15 & 7) << 4;
#pragma unroll
      for (int kk = 0; kk < 2; ++kk)
        af[i][kk] = *(const short8*)(ab + row * 128 + ((kk * 64 + lg * 16) ^ rx));
    }
#pragma unroll
    for (int i = 0; i < 4; ++i) {
      const int row = wn * 64 + i * 16 + l15;
      const int rx = (l15 & 7) << 4;
#pragma unroll
      for (int kk = 0; kk < 2; ++kk)
        bf[i][kk] = *(const short8*)(bb + row * 128 + ((kk * 64 + lg * 16) ^ rx));
    }
    __builtin_amdgcn_s_setprio(1);
#pragma unroll
    for (int kk = 0; kk < 2; ++kk)
#pragma unroll
      for (int im = 0; im < 4; ++im)
#pragma unroll
        for (int in = 0; in < 4; ++in)
          acc[im][in] = __builtin_amdgcn_mfma_f32_16x16x32_bf16(af[im][kk], bf[in][kk],
                                                                acc[im][in], 0, 0, 0);
    __builtin_amdgcn_s_setprio(0);
    __builtin_amdgcn_sched_barrier(0);
    __builtin_amdgcn_s_barrier();  // all reads of buf[cur] done before restage
    cur ^= 1;
  }

#pragma unroll
  for (int im = 0; im < 4; ++im) {
#pragma unroll
    for (int in = 0; in < 4; ++in) {
      const int gn = n0 + wn * 64 + in * 16 + l15;
#pragma unroll
      for (int r = 0; r < 4; ++r) {
        const int gm = m0 + wm * 64 + im * 16 + lg * 4 + r;
        float v = acc[im][in][r];
        if (EP == 0) {
          v += bias[gn];
          const int sel = gn / DDIM;
          const int d = gn - sel * DDIM;
          const int h = d >> 6, dh = d & 63;
          const int bb2 = gm >> 10, ss = gm & 1023;
          const u16 bv = f2b(v);
          const int bhid = bb2 * HEADS + h;
          if (sel == 0)      o0[((size_t)bhid * SDIM + ss) * DHD + dh] = bv;
          else if (sel == 1) o1[((size_t)bhid * SDIM + ss) * DHD + dh] = bv;
          else               o2[((size_t)bhid * DHD + dh) * SDIM + ss] = bv;
        } else if (EP == 1) {
          const size_t idx = (size_t)gm * N + gn;
          outF[idx] = v + bias[gn] + res[idx];
        } else {
          const size_t idx = (size_t)gm * N + gn;
          o0[idx] = f2b(fmaxf(v + bias[gn], 0.f));
        }
      }
    }
  }
}

// ---- flash attention for q rows < 512: grid (8, B*H), 4 waves x 16 q-rows ----
__global__ __launch_bounds__(256) void attn_kernel(const u16* __restrict__ Q,
                                                   const u16* __restrict__ Km,
                                                   const u16* __restrict__ Vt,
                                                   u16* __restrict__ ctx) {
  __shared__ u16 Ks[2][4096];
  __shared__ u16 Vs[2][4096];
  __shared__ u16 P_lds[4][16][72];
  const int bh = blockIdx.y;
  const int tid = threadIdx.x;
  const int wid = tid >> 6, lane = tid & 63;
  const int l15 = lane & 15, lg = lane >> 4;
  const int q0 = blockIdx.x * 64 + wid * 16;

  const u16* Qp = Q + (size_t)bh * SDIM * DHD;
  const char* Kp = (const char*)(Km + (size_t)bh * SDIM * DHD);
  const char* Vp = (const char*)(Vt + (size_t)bh * DHD * SDIM);

  int so[2], vo_base[2], ldso[2];
#pragma unroll
  for (int j = 0; j < 2; ++j) {
    const int o = j * 4096 + tid * 16;
    const int row = o >> 7;
    ldso[j] = o;
    so[j] = o ^ ((row & 7) << 4);
    vo_base[j] = row * 2048 + ((o & 127) ^ ((row & 7) << 4));
  }

  short8 aq0 = *(const short8*)&Qp[(q0 + l15) * DHD + 8 * lg];
  short8 aq1 = *(const short8*)&Qp[(q0 + l15) * DHD + 32 + 8 * lg];

  float mrow[4], lrow[4];
  f32x4 o_acc[4] = {};
#pragma unroll
  for (int r = 0; r < 4; ++r) { mrow[r] = -1e30f; lrow[r] = 0.f; }

#pragma unroll
  for (int j = 0; j < 2; ++j) {
    GLDS16(Kp + so[j], (char*)&Ks[0][0] + ldso[j]);
    GLDS16(Vp + vo_base[j], (char*)&Vs[0][0] + ldso[j]);
  }

  for (int kb = 0; kb < 16; ++kb) {
    const int cur = kb & 1;
    if (kb < 15) {
#pragma unroll
      for (int j = 0; j < 2; ++j) {
        GLDS16(Kp + (size_t)(kb + 1) * 8192 + so[j], (char*)&Ks[cur ^ 1][0] + ldso[j]);
        GLDS16(Vp + (size_t)(kb + 1) * 128 + vo_base[j], (char*)&Vs[cur ^ 1][0] + ldso[j]);
      }
      asm volatile("s_waitcnt vmcnt(4)" ::: "memory");
    } else {
      asm volatile("s_waitcnt vmcnt(0)" ::: "memory");
    }
    __builtin_amdgcn_s_barrier();
    __builtin_amdgcn_sched_barrier(0);

    f32x4 s_acc[4] = {};
#pragma unroll
    for (int in = 0; in < 4; ++in) {
      const int row = in * 16 + l15;
      const int a0 = (row * 128 + lg * 16) ^ ((row & 7) << 4);
      const int a1 = (row * 128 + 64 + lg * 16) ^ ((row & 7) << 4);
      short8 b0 = *(const short8*)((const char*)&Ks[cur][0] + a0);
      short8 b1 = *(const short8*)((const char*)&Ks[cur][0] + a1);
      s_acc[in] = __builtin_amdgcn_mfma_f32_16x16x32_bf16(aq0, b0, s_acc[in], 0, 0, 0);
      s_acc[in] = __builtin_amdgcn_mfma_f32_16x16x32_bf16(aq1, b1, s_acc[in], 0, 0, 0);
    }
#pragma unroll
    for (int in = 0; in < 4; ++in)
#pragma unroll
      for (int r = 0; r < 4; ++r) s_acc[in][r] *= 0.125f;

    float alpha[4], rsum[4];
#pragma unroll
    for (int r = 0; r < 4; ++r) {
      float v = -1e30f;
#pragma unroll
      for (int in = 0; in < 4; ++in) v = fmaxf(v, s_acc[in][r]);
#pragma unroll
      for (int m = 1; m < 16; m <<= 1) v = fmaxf(v, __shfl_xor(v, m, 64));
      const float mn = fmaxf(mrow[r], v);
      alpha[r] = __expf(mrow[r] - mn);
      mrow[r] = mn;
      rsum[r] = 0.f;
    }
#pragma unroll
    for (int in = 0; in < 4; ++in)
#pragma unroll
      for (int r = 0; r < 4; ++r) {
        const float p = __expf(s_acc[in][r] - mrow[r]);
        rsum[r] += p;
        P_lds[wid][lg * 4 + r][in * 16 + l15] = f2b(p);
      }
#pragma unroll
    for (int r = 0; r < 4; ++r) {
      float v = rsum[r];
#pragma unroll
      for (int m = 1; m < 16; m <<= 1) v += __shfl_xor(v, m, 64);
      lrow[r] = lrow[r] * alpha[r] + v;
    }
#pragma unroll
    for (int in = 0; in < 4; ++in)
#pragma unroll
      for (int r = 0; r < 4; ++r) o_acc[in][r] *= alpha[r];

    short8 ap0 = *(const short8*)&P_lds[wid][l15][8 * lg];
    short8 ap1 = *(const short8*)&P_lds[wid][l15][32 + 8 * lg];

#pragma unroll
    for (int in = 0; in < 4; ++in) {
      const int row = in * 16 + l15;
      const int a0 = (row * 128 + lg * 16) ^ ((row & 7) << 4);
      const int a1 = (row * 128 + 64 + lg * 16) ^ ((row & 7) << 4);
      short8 b0 = *(const short8*)((const char*)&Vs[cur][0] + a0);
      short8 b1 = *(const short8*)((const char*)&Vs[cur][0] + a1);
      o_acc[in] = __builtin_amdgcn_mfma_f32_16x16x32_bf16(ap0, b0, o_acc[in], 0, 0, 0);
      o_acc[in] = __builtin_amdgcn_mfma_f32_16x16x32_bf16(ap1, b1, o_acc[in], 0, 0, 0);
    }
    __builtin_amdgcn_sched_barrier(0);
    __builtin_amdgcn_s_barrier();
    __builtin_amdgcn_sched_barrier(0);
  }

  const int bb = bh / HEADS, h = bh - bb * HEADS;
#pragma unroll
  for (int in = 0; in < 4; ++in)
#pragma unroll
    for (int r = 0; r < 4; ++r) {
      const int s = q0 + lg * 4 + r;
      const float v = o_acc[in][r] / lrow[r];
      ctx[((size_t)(bb * SDIM + s)) * DDIM + h * 64 + in * 16 + l15] = f2b(v);
    }
}

// ---- rows >= 512: uniform attention = column-mean of V. grid (B*H), 256 thr ----
__global__ __launch_bounds__(256) void meanv_kernel(const u16* __restrict__ Vt,
                                                    u16* __restrict__ ctx) {
  __shared__ float mean_s[64];
  const int bh = blockIdx.x;
  const int t = threadIdx.x;
  const int dh = t >> 2, part = t & 3;
  const u16* vp = Vt + (size_t)bh * DHD * SDIM + (size_t)dh * SDIM + part * 256;
  float s = 0.f;
#pragma unroll
  for (int i = 0; i < 32; ++i) {
    short8 v = *(const short8*)&vp[i * 8];
#pragma unroll
    for (int j = 0; j < 8; ++j) s += b2f((u16)v[j]);
  }
  s += __shfl_xor(s, 1, 64);
  s += __shfl_xor(s, 2, 64);
  if (part == 0) mean_s[dh] = s * (1.f / 1024.f);
  __syncthreads();
  const int b = bh / HEADS, h = bh - b * HEADS;
  u16x4 val;
#pragma unroll
  for (int j = 0; j < 4; ++j) val[j] = f2b(mean_s[(t & 15) * 4 + j]);
#pragma unroll
  for (int i = 0; i < 32; ++i) {
    const int row = 512 + i * 16 + (t >> 4);
    *(u16x4*)&ctx[((size_t)(b * SDIM + row)) * DDIM + h * 64 + (t & 15) * 4] = val;
  }
}

extern "C" void kernel_launch(void* const* d_in, const int* in_sizes, int n_in,
                              void* d_out, int out_size, void* d_ws, size_t ws_size,
                              hipStream_t stream) {
  const float* x    = (const float*)d_in[0];
  const float* Wq   = (const float*)d_in[1];
  const float* bq   = (const float*)d_in[2];
  const float* Wk   = (const float*)d_in[3];
  const float* bk   = (const float*)d_in[4];
  const float* Wv   = (const float*)d_in[5];
  const float* bv   = (const float*)d_in[6];
  const float* Wo   = (const float*)d_in[7];
  const float* bo   = (const float*)d_in[8];
  const float* ln1g = (const float*)d_in[9];
  const float* ln1b = (const float*)d_in[10];
  const float* ln2g = (const float*)d_in[11];
  const float* ln2b = (const float*)d_in[12];
  const float* W1   = (const float*)d_in[13];
  const float* b1   = (const float*)d_in[14];
  const float* W2   = (const float*)d_in[15];
  const float* b2   = (const float*)d_in[16];

  char* ws = (char*)d_ws;
  u16* xn1   = (u16*)(ws + 0);
  u16* qb    = (u16*)(ws + 12582912);
  u16* kbuf  = (u16*)(ws + 25165824);
  u16* vtb   = (u16*)(ws + 37748736);
  u16* h1    = (u16*)(ws + 0);  // overlays xn1/q/k/vT (all dead by MLP1)
  u16* ctx   = (u16*)(ws + 50331648);
  float* x2  = (float*)(ws + 62914560);
  u16* xn2   = (u16*)(ws + 88080384);
  u16* wqkvT = (u16*)(ws + 100663296);
  u16* woT   = (u16*)(ws + 104202240);
  u16* w1T   = (u16*)(ws + 105381888);
  u16* w2T   = (u16*)(ws + 110100480);
  float* bqkv = (float*)(ws + 114819072);

  transpose_w<<<dim3(24, 24), 256, 0, stream>>>(Wq, wqkvT, 768, 768);
  transpose_w<<<dim3(24, 24), 256, 0, stream>>>(Wk, wqkvT + 768 * 768, 768, 768);
  transpose_w<<<dim3(24, 24), 256, 0, stream>>>(Wv, wqkvT + 2 * 768 * 768, 768, 768);
  transpose_w<<<dim3(24, 24), 256, 0, stream>>>(Wo, woT, 768, 768);
  transpose_w<<<dim3(96, 24), 256, 0, stream>>>(W1, w1T, 768, 3072);
  transpose_w<<<dim3(24, 96), 256, 0, stream>>>(W2, w2T, 3072, 768);
  bias_concat<<<9, 256, 0, stream>>>(bq, bk, bv, bqkv);

  ln_kernel<<<2048, 256, 0, stream>>>(x, ln1g, ln1b, xn1);
  gemm_bf16<0><<<dim3(64, 18), 256, 0, stream>>>(xn1, wqkvT, 8192, 2304, 768,
                                                 bqkv, nullptr, nullptr, qb, kbuf, vtb);
  attn_kernel<<<dim3(8, 96), 256, 0, stream>>>(qb, kbuf, vtb, ctx);
  meanv_kernel<<<96, 256, 0, stream>>>(vtb, ctx);
  gemm_bf16<1><<<dim3(64, 6), 256, 0, stream>>>(ctx, woT, 8192, 768, 768,
                                                bo, x, x2, nullptr, nullptr, nullptr);
  ln_kernel<<<2048, 256, 0, stream>>>(x2, ln2g, ln2b, xn2);
  gemm_bf16<2><<<dim3(64, 24), 256, 0, stream>>>(xn2, w1T, 8192, 3072, 768,
                                                 b1, nullptr, nullptr, h1, nullptr, nullptr);
  gemm_bf16<1><<<dim3(64, 6), 256, 0, stream>>>(h1, w2T, 8192, 768, 3072,
                                                b2, x2, (float*)d_out, nullptr, nullptr, nullptr);
}